// Round 2
// baseline (1491.705 us; speedup 1.0000x reference)
//
#include <hip/hip_runtime.h>
#include <hip/hip_bf16.h>

typedef __bf16 bf16x8 __attribute__((ext_vector_type(8)));
typedef float f32x4 __attribute__((ext_vector_type(4)));
typedef unsigned short ushort_t;

#define NN 8192
#define DD 128
#define KTOT 24576
#define KCHUNKS 8          // k-chunks per m-tile (block-level)
#define KCHUNK 3072        // KTOT / KCHUNKS, split across 4 waves -> 768/wave
#define MTILES 256         // 8192 / 32 rows per block

// ---------------------------------------------------------------------------
// Kernel 1 (rewritten, MFMA): B_cat[r][n] = sum_c x[r&8191][c]*sd[r>>13][c]*W[c][n]
// Stored bf16 in MFMA-16x16x32 B-fragment order:
//   Bws[(((r>>5)*8 + (n>>4))*64 + ((r>>3&3)*16 + (n&15)))*8 + (r&7)]
// Each wave: 16 x-rows, A-frags direct from global x, B-frags from L1-hot W*sd.
// ---------------------------------------------------------------------------
__global__ __launch_bounds__(256) void bprep_kernel(
    const float* __restrict__ x, const float* __restrict__ W,
    const float* __restrict__ sd0, const float* __restrict__ sd1,
    const float* __restrict__ sd2, ushort_t* __restrict__ Bws)
{
    const int lane  = threadIdx.x & 63;
    const int wave  = threadIdx.x >> 6;
    const int m15   = lane & 15;
    const int q     = lane >> 4;
    const int xrow0 = blockIdx.x * 64 + wave * 16;   // 128 blocks cover 8192 rows

    // A fragments: Af[kt], lane holds x[xrow0+m15][kt*32 + q*8 + j]
    bf16x8 Af[4];
#pragma unroll
    for (int kt = 0; kt < 4; ++kt) {
        const float* ap = x + (size_t)(xrow0 + m15) * DD + kt * 32 + q * 8;
        float4 f0 = *reinterpret_cast<const float4*>(ap);
        float4 f1 = *reinterpret_cast<const float4*>(ap + 4);
        bf16x8 a;
        a[0] = (__bf16)f0.x; a[1] = (__bf16)f0.y;
        a[2] = (__bf16)f0.z; a[3] = (__bf16)f0.w;
        a[4] = (__bf16)f1.x; a[5] = (__bf16)f1.y;
        a[6] = (__bf16)f1.z; a[7] = (__bf16)f1.w;
        Af[kt] = a;
    }

    const float* sds0 = sd0;
#pragma unroll
    for (int sup = 0; sup < 3; ++sup) {
        const float* sd = (sup == 0) ? sds0 : ((sup == 1) ? sd1 : sd2);
        // hoist per-lane sd values: sdv[kt][j] = sd[kt*32 + q*8 + j]
        float sdv[4][8];
#pragma unroll
        for (int kt = 0; kt < 4; ++kt)
#pragma unroll
            for (int j = 0; j < 8; ++j)
                sdv[kt][j] = sd[kt * 32 + q * 8 + j];

#pragma unroll
        for (int nt = 0; nt < 8; ++nt) {
            f32x4 acc = (f32x4){0.f, 0.f, 0.f, 0.f};
#pragma unroll
            for (int kt = 0; kt < 4; ++kt) {
                bf16x8 Bf;
#pragma unroll
                for (int j = 0; j < 8; ++j) {
                    int c = kt * 32 + q * 8 + j;
                    float v = sdv[kt][j] * W[(size_t)c * DD + nt * 16 + m15];
                    Bf[j] = (__bf16)v;
                }
                acc = __builtin_amdgcn_mfma_f32_16x16x32_bf16(Af[kt], Bf, acc, 0, 0, 0);
            }
            // D layout: row(q*4+rr) = x-row offset, col(m15) -> n = nt*16+m15
            int rb = sup * NN + xrow0 + q * 4;       // 4 consecutive k-rows of B_cat
            int cc = rb >> 5;
            int j0 = rb & 7;                          // 0 or 4
            int hi = (rb >> 3) & 3;
            size_t base = ((((size_t)cc * 8 + nt) * 64) + hi * 16 + m15) * 8 + j0;
            union { ushort_t u[4]; unsigned long long v; } p;
#pragma unroll
            for (int rr = 0; rr < 4; ++rr) {
                __bf16 b = (__bf16)acc[rr];
                __builtin_memcpy(&p.u[rr], &b, sizeof(ushort_t));
            }
            *reinterpret_cast<unsigned long long*>(Bws + base) = p.v;
        }
    }
}

// ---------------------------------------------------------------------------
// Kernel 2: out += S_cat[8192 x 24576] @ B_cat[24576 x 128]
// 2048 blocks (256 m-tiles x 8 k-chunks). Block = 32 rows; 4 waves split the
// 3072-col k-chunk (768 each). LDS reduce across waves, then one coalesced
// global atomicAdd set per block (8.4M atomics total, same as round 1).
// ---------------------------------------------------------------------------
__global__ __launch_bounds__(256, 8) void spmm_kernel(
    const float* __restrict__ s0, const float* __restrict__ s1,
    const float* __restrict__ s2, const ushort_t* __restrict__ Bws,
    float* __restrict__ out)
{
    __shared__ float red[32 * DD];                 // 16 KB
    const int lane   = threadIdx.x & 63;
    const int wave   = threadIdx.x >> 6;
    const int mtile  = blockIdx.x >> 3;
    const int kchunk = blockIdx.x & 7;             // low bits -> per-XCD B locality
    const int m15    = lane & 15;
    const int q      = lane >> 4;
    const int row0   = mtile * 32;
    const int kbase  = kchunk * KCHUNK + wave * 768;

    f32x4 acc[2][8];
#pragma unroll
    for (int ms = 0; ms < 2; ++ms)
#pragma unroll
        for (int t = 0; t < 8; ++t)
            acc[ms][t] = (f32x4){0.f, 0.f, 0.f, 0.f};

    const bf16x8* __restrict__ Bv = reinterpret_cast<const bf16x8*>(Bws);

#pragma unroll 2
    for (int c = 0; c < 24; ++c) {
        const int kg  = kbase + c * 32;
        const int sup = kg >> 13;
        const float* sp = (sup == 0) ? s0 : ((sup == 1) ? s1 : s2);
        const int koff = (kg & (NN - 1)) + q * 8;

        bf16x8 af[2];
#pragma unroll
        for (int ms = 0; ms < 2; ++ms) {
            const float* ap = sp + (size_t)(row0 + ms * 16 + m15) * NN + koff;
            float4 f0 = *reinterpret_cast<const float4*>(ap);
            float4 f1 = *reinterpret_cast<const float4*>(ap + 4);
            bf16x8 a;
            a[0] = (__bf16)f0.x; a[1] = (__bf16)f0.y;
            a[2] = (__bf16)f0.z; a[3] = (__bf16)f0.w;
            a[4] = (__bf16)f1.x; a[5] = (__bf16)f1.y;
            a[6] = (__bf16)f1.z; a[7] = (__bf16)f1.w;
            af[ms] = a;
        }

        const bf16x8* bp = Bv + ((size_t)(kg >> 5)) * 512 + lane;
#pragma unroll
        for (int t = 0; t < 8; ++t) {
            bf16x8 bf = bp[(size_t)t * 64];
            acc[0][t] = __builtin_amdgcn_mfma_f32_16x16x32_bf16(af[0], bf, acc[0][t], 0, 0, 0);
            acc[1][t] = __builtin_amdgcn_mfma_f32_16x16x32_bf16(af[1], bf, acc[1][t], 0, 0, 0);
        }
    }

    // --- epilogue: LDS reduce across the block's 4 waves ---
#pragma unroll
    for (int i = 0; i < 16; ++i)
        red[threadIdx.x + i * 256] = 0.f;
    __syncthreads();

    // C/D layout (m89-verified): col = lane&15, row = (lane>>4)*4 + reg
#pragma unroll
    for (int ms = 0; ms < 2; ++ms)
#pragma unroll
        for (int t = 0; t < 8; ++t)
#pragma unroll
            for (int r = 0; r < 4; ++r) {
                int row = ms * 16 + q * 4 + r;
                int col = t * 16 + m15;
                atomicAdd(&red[row * DD + col], acc[ms][t][r]);
            }
    __syncthreads();

    float* og = out + (size_t)row0 * DD;
#pragma unroll
    for (int i = 0; i < 16; ++i) {
        int e = threadIdx.x + i * 256;
        atomicAdd(og + e, red[e]);
    }
}

// ---------------------------------------------------------------------------
// Kernel 3: in-place relu on d_out
// ---------------------------------------------------------------------------
__global__ __launch_bounds__(256) void relu_kernel(float4* __restrict__ out)
{
    int i = blockIdx.x * 256 + threadIdx.x;
    float4 v = out[i];
    v.x = fmaxf(v.x, 0.f);
    v.y = fmaxf(v.y, 0.f);
    v.z = fmaxf(v.z, 0.f);
    v.w = fmaxf(v.w, 0.f);
    out[i] = v;
}

extern "C" void kernel_launch(void* const* d_in, const int* in_sizes, int n_in,
                              void* d_out, int out_size, void* d_ws, size_t ws_size,
                              hipStream_t stream)
{
    (void)in_sizes; (void)n_in; (void)ws_size;
    const float* x   = (const float*)d_in[0];
    const float* s0  = (const float*)d_in[1];
    const float* s1  = (const float*)d_in[2];
    const float* s2  = (const float*)d_in[3];
    const float* W   = (const float*)d_in[4];
    const float* sd0 = (const float*)d_in[5];
    const float* sd1 = (const float*)d_in[6];
    const float* sd2 = (const float*)d_in[7];
    float* out = (float*)d_out;
    ushort_t* Bws = (ushort_t*)d_ws;   // 24576*128*2 = 6.3 MB

    hipMemsetAsync(d_out, 0, (size_t)out_size * sizeof(float), stream);
    bprep_kernel<<<NN / 64, 256, 0, stream>>>(x, W, sd0, sd1, sd2, Bws);
    spmm_kernel<<<MTILES * KCHUNKS, 256, 0, stream>>>(s0, s1, s2, Bws, out);
    relu_kernel<<<out_size / 1024, 256, 0, stream>>>((float4*)d_out);
}